// Round 19
// baseline (144.732 us; speedup 1.0000x reference)
//
#include <hip/hip_runtime.h>
#include <math.h>

// ConvCaps EM routing, fp32 I/O. n=392 positions, one 512-thread block each.
// R17 = R16 source (2-way k-interleave in sweeps 1-2) + __launch_bounds__(512,1).
// R16 post-mortem: at default bounds the compiler pinned VGPR=84 and
// SERIALIZED the two interleaved chains (VALUBusy 42->30, dur 76->97).
// Measured toolchain rule (R3: (1024,8)->32 VGPR; R8: (512,4)->64): VGPR cap
// = 256/min_waves. So (512,1) -> 256-VGPR budget: the ~150-reg live set of
// two concurrent chains fits. Deliberate TLP->ILP trade: 8 waves/CU instead
// of 16, justified because measurement shows chain-bound (wall/iter ~1690cy
// vs issue ~710cy): two in-flight softmax chains halve effective chain/k.
// R12 lesson: no LDS register-prefetch. Watch: WRITE_SIZE balloon = spill.
// (R19: third submission of this source. R17/R18 were broker-level container
// failures with zero kernel output; precedent R13/R14 fail -> R15 pass says
// retry identical. If this fails again, R20 reverts to measured-best R15.)

#define NTH 512
#define KK 288
#define KT 18         // 288 / 16 k-groups
#define CC 32
#define PS 16
#define EPSF 1e-8f
#define LAMF 1e-3f
#define HL2PI 0.91893853320467274178f   // 0.5*ln(2*pi)
#define LOG2E 1.4426950408889634f

typedef float v2f __attribute__((ext_vector_type(2)));

__device__ __forceinline__ float4 ld4(const float* p){ return *(const float4*)p; }
__device__ __forceinline__ float rcpf(float x){ return __builtin_amdgcn_rcpf(x); }
__device__ __forceinline__ v2f bc2(float s){ return (v2f){s, s}; }
__device__ __forceinline__ v2f fma2(v2f a, v2f b, v2f c){ return __builtin_elementwise_fma(a, b, c); }

// DPP cross-lane reduce steps (VALU pipe ~2-4cyc vs ds_swizzle ~30cyc).
template<int CTRL>
__device__ __forceinline__ float dpp_add(float x){
  const int p = __builtin_amdgcn_update_dpp(0, __builtin_bit_cast(int, x),
                                            CTRL, 0xF, 0xF, true);
  return x + __builtin_bit_cast(float, p);
}
template<int CTRL>
__device__ __forceinline__ float dpp_max(float x){
  const int p = __builtin_amdgcn_update_dpp(0, __builtin_bit_cast(int, x),
                                            CTRL, 0xF, 0xF, true);
  return fmaxf(x, __builtin_bit_cast(float, p));
}

extern "C" __global__ void __launch_bounds__(NTH, 1)
convcaps_em_kernel(const float* __restrict__ x, const float* __restrict__ wgt,
                   const float* __restrict__ beta_a, const float* __restrict__ beta_u,
                   float* __restrict__ out)
{
  __shared__ float sP[KK*PS];        // poses, xor-swizzled groups (18432 B)
  __shared__ float sA[KK];           // f = a/(a+eps) (1152 B)
  __shared__ float sPart[8*CC*33];   // wave partials t0|t1[16]|t2[16] (33792 B)
  __shared__ float sMu[CC*17];       // (2176 B)
  __shared__ float sNI2[CC*17];      // -0.5/sigma^2 (2176 B)
  __shared__ float sLs[CC], sLnA[CC], sAo[CC];   // 384 B

  const int tid = threadIdx.x;
  const int n   = blockIdx.x;
  const int b   = n / 49;
  const int r49 = n - b*49;
  const int ohi = r49 / 7;
  const int owi = r49 - ohi*7;

  const float* xw = x + ((size_t)b*16 + (size_t)(ohi*2))*16*544 + (size_t)(owi*2)*544;

  const int c  = tid & 31;    // sweep layout: c in-wave (softmax over c)
  const int ks = tid >> 5;    // k-group 0..15
  const int w  = tid >> 6;    // wave 0..7
  const int cc = tid >> 4;    // stats layout: one thread per (cc, pp)
  const int pp = tid & 15;

  // ---- stage poses (xor-swizzled groups) ----
  for (int idx = tid; idx < KK*PS/4; idx += NTH) {   // 1152 float4s
    const int sp  = idx >> 7;
    const int ch4 = idx & 127;
    const int kh = sp/3, kw = sp - kh*3;
    const float4 v = ld4(&xw[kh*(16*544) + kw*544 + ch4*4]);
    const int k = sp*32 + (ch4 >> 2);
    const int g = ch4 & 3;
    *(float4*)&sP[(k<<4) + ((g ^ ((k>>1)&3))<<2)] = v;
  }
  // ---- stage activations ----
  if (tid < KK/4) {
    const int sp  = tid >> 3;
    const int bc4 = tid & 7;
    const int kh = sp/3, kw = sp - kh*3;
    const float4 v = ld4(&xw[kh*(16*544) + kw*544 + 512 + bc4*4]);
    *(float4*)&sA[sp*32 + bc4*4] = v;
  }
  __syncthreads();
  if (tid < KK) { const float a = sA[tid]; sA[tid] = a * rcpf(a + EPSF); }
  __syncthreads();

  float t0;
  v2f t1[8], t2[8];    // packed moment accumulators

  // ---- stats phase (R6-proven layout; unpack pairs at store) ----
  auto stats = [&](){
    t0 += __shfl_xor(t0, 32);
#pragma unroll
    for (int q = 0; q < 8; ++q) {
      t1[q].x += __shfl_xor(t1[q].x, 32);
      t1[q].y += __shfl_xor(t1[q].y, 32);
      t2[q].x += __shfl_xor(t2[q].x, 32);
      t2[q].y += __shfl_xor(t2[q].y, 32);
    }
    if ((tid & 32) == 0) {
      float* pr = &sPart[(w*CC + c)*33];
      pr[0] = t0;
#pragma unroll
      for (int q = 0; q < 8; ++q) {
        pr[1 + 2*q]     = t1[q].x;  pr[1 + 2*q + 1]  = t1[q].y;
        pr[17 + 2*q]    = t2[q].x;  pr[17 + 2*q + 1] = t2[q].y;
      }
    }
    __syncthreads();
    {
      float T0 = 0.f, T1 = 0.f, T2 = 0.f;
#pragma unroll
      for (int j = 0; j < 8; ++j) {
        const float* pr = &sPart[(j*CC + cc)*33];
        T0 += pr[0]; T1 += pr[1+pp]; T2 += pr[17+pp];
      }
      const float z   = rcpf(T0 + EPSF);
      const float mu  = T1 * z;
      const float s0  = T0 * z;
      const float var = fmaxf(T2*z - mu*mu*(2.f - s0), 0.f) + EPSF;
      sMu[cc*17 + pp]  = mu;
      sNI2[cc*17 + pp] = -0.5f * rcpf(var);
      float lsum = 0.5f * __logf(var);
      lsum = dpp_add<0xB1>(lsum); lsum = dpp_add<0x4E>(lsum);
      lsum = dpp_add<0x141>(lsum); lsum = dpp_add<0x140>(lsum);
      if (pp == 0) {
        const float cost = (16.f*beta_u[cc] + lsum) * T0;   // r_sum = T0
        const float ao = rcpf(1.f + __expf(-(LAMF*(beta_a[cc] - cost))));
        sAo[cc] = ao; sLnA[cc] = __logf(ao); sLs[cc] = lsum;
      }
    }
    __syncthreads();
  };

  const float4* wg4 = (const float4*)wgt;

  // ---- sweep 0 (it=0): r uniform -> rr = f/32, W software-pipelined ----
  t0 = 0.f;
#pragma unroll
  for (int q = 0; q < 8; ++q) { t1[q] = bc2(0.f); t2[q] = bc2(0.f); }
  {
    float4 cw0, cw1, cw2, cw3;
    {
      const size_t base = ((size_t)(ks*32 + c))*4;   // kt=0 -> k=ks
      cw0 = wg4[base]; cw1 = wg4[base+1]; cw2 = wg4[base+2]; cw3 = wg4[base+3];
    }
    for (int kt = 0; kt < KT; ++kt) {
      const int k = kt*16 + ks;
      const int kn = ((kt+1 < KT) ? kt+1 : kt)*16 + ks;
      float4 nw0, nw1, nw2, nw3;
      {
        const size_t base = ((size_t)(kn*32 + c))*4;
        nw0 = wg4[base]; nw1 = wg4[base+1]; nw2 = wg4[base+2]; nw3 = wg4[base+3];
      }
      const v2f w0lo = {cw0.x,cw0.y}, w0hi = {cw0.z,cw0.w};
      const v2f w1lo = {cw1.x,cw1.y}, w1hi = {cw1.z,cw1.w};
      const v2f w2lo = {cw2.x,cw2.y}, w2hi = {cw2.z,cw2.w};
      const v2f w3lo = {cw3.x,cw3.y}, w3hi = {cw3.z,cw3.w};
      const int sw = (k>>1)&3;
      const float* pb = &sP[k<<4];
      const float4 Pi[4] = { ld4(pb + ((0^sw)<<2)), ld4(pb + ((1^sw)<<2)),
                             ld4(pb + ((2^sw)<<2)), ld4(pb + ((3^sw)<<2)) };
      const float rr = sA[k] * (1.0f/32.0f);
      t0 += rr;
      const v2f rr2 = bc2(rr);
#pragma unroll
      for (int i = 0; i < 4; ++i) {
        v2f lo = bc2(Pi[i].x) * w0lo;
        lo = fma2(bc2(Pi[i].y), w1lo, lo);
        lo = fma2(bc2(Pi[i].z), w2lo, lo);
        lo = fma2(bc2(Pi[i].w), w3lo, lo);
        v2f hi = bc2(Pi[i].x) * w0hi;
        hi = fma2(bc2(Pi[i].y), w1hi, hi);
        hi = fma2(bc2(Pi[i].z), w2hi, hi);
        hi = fma2(bc2(Pi[i].w), w3hi, hi);
        const v2f mlo = rr2 * lo, mhi = rr2 * hi;
        t1[i*2]   += mlo;  t2[i*2]   = fma2(mlo, lo, t2[i*2]);
        t1[i*2+1] += mhi;  t2[i*2+1] = fma2(mhi, hi, t2[i*2+1]);
      }
      cw0 = nw0; cw1 = nw1; cw2 = nw2; cw3 = nw3;
    }
  }
  stats();

  // ---- sweeps 1,2: 2-way k-interleave; exponent = Sum (A*v+B)*v + G ----
  for (int it = 1; it < 3; ++it) {
    v2f A2[8], B2[8];
    float gsum = 0.f;
#pragma unroll
    for (int q = 0; q < 8; ++q) {
      const v2f m2 = (v2f){ sMu[c*17 + 2*q],  sMu[c*17 + 2*q + 1] };
      const v2f n2 = (v2f){ sNI2[c*17 + 2*q], sNI2[c*17 + 2*q + 1] };
      const v2f nm = n2 * m2;
      A2[q] = bc2(LOG2E) * n2;
      B2[q] = bc2(-2.f*LOG2E) * nm;
      const v2f g2 = nm * m2;
      gsum += g2.x + g2.y;
    }
    float lcv = sLnA[c] - sLs[c] - 16.f*HL2PI;
    float M = lcv;
    M = dpp_max<0xB1>(M);  M = dpp_max<0x4E>(M);
    M = dpp_max<0x141>(M); M = dpp_max<0x140>(M);
    M = fmaxf(M, __shfl_xor(M, 16));
    const float G = LOG2E*(gsum + lcv - M);
    t0 = 0.f;
#pragma unroll
    for (int q = 0; q < 8; ++q) { t1[q] = bc2(0.f); t2[q] = bc2(0.f); }
    for (int kt = 0; kt < KT; kt += 2) {
      const int kA = kt*16 + ks;
      const int kB = kA + 16;
      // both W tiles issued together: each covers the other's L2 latency
      const float4* wgA = wg4 + ((size_t)(kA*32 + c))*4;
      const float4* wgB = wg4 + ((size_t)(kB*32 + c))*4;
      const float4 aw0 = wgA[0], aw1 = wgA[1], aw2 = wgA[2], aw3 = wgA[3];
      const float4 bw0 = wgB[0], bw1 = wgB[1], bw2 = wgB[2], bw3 = wgB[3];
      const int swA = (kA>>1)&3, swB = (kB>>1)&3;
      const float* pbA = &sP[kA<<4];
      const float* pbB = &sP[kB<<4];
      const float4 PA[4] = { ld4(pbA + ((0^swA)<<2)), ld4(pbA + ((1^swA)<<2)),
                             ld4(pbA + ((2^swA)<<2)), ld4(pbA + ((3^swA)<<2)) };
      const float4 PB[4] = { ld4(pbB + ((0^swB)<<2)), ld4(pbB + ((1^swB)<<2)),
                             ld4(pbB + ((2^swB)<<2)), ld4(pbB + ((3^swB)<<2)) };
      v2f vA[8], vB[8];
#pragma unroll
      for (int i = 0; i < 4; ++i) {
        v2f lo = bc2(PA[i].x) * (v2f){aw0.x,aw0.y};
        lo = fma2(bc2(PA[i].y), (v2f){aw1.x,aw1.y}, lo);
        lo = fma2(bc2(PA[i].z), (v2f){aw2.x,aw2.y}, lo);
        lo = fma2(bc2(PA[i].w), (v2f){aw3.x,aw3.y}, lo);
        v2f hi = bc2(PA[i].x) * (v2f){aw0.z,aw0.w};
        hi = fma2(bc2(PA[i].y), (v2f){aw1.z,aw1.w}, hi);
        hi = fma2(bc2(PA[i].z), (v2f){aw2.z,aw2.w}, hi);
        hi = fma2(bc2(PA[i].w), (v2f){aw3.z,aw3.w}, hi);
        vA[i*2] = lo; vA[i*2+1] = hi;
      }
#pragma unroll
      for (int i = 0; i < 4; ++i) {
        v2f lo = bc2(PB[i].x) * (v2f){bw0.x,bw0.y};
        lo = fma2(bc2(PB[i].y), (v2f){bw1.x,bw1.y}, lo);
        lo = fma2(bc2(PB[i].z), (v2f){bw2.x,bw2.y}, lo);
        lo = fma2(bc2(PB[i].w), (v2f){bw3.x,bw3.y}, lo);
        v2f hi = bc2(PB[i].x) * (v2f){bw0.z,bw0.w};
        hi = fma2(bc2(PB[i].y), (v2f){bw1.z,bw1.w}, hi);
        hi = fma2(bc2(PB[i].z), (v2f){bw2.z,bw2.w}, hi);
        hi = fma2(bc2(PB[i].w), (v2f){bw3.z,bw3.w}, hi);
        vB[i*2] = lo; vB[i*2+1] = hi;
      }
      v2f accA = bc2(0.f), accB = bc2(0.f);
#pragma unroll
      for (int q = 0; q < 8; ++q) {
        const v2f hA = fma2(A2[q], vA[q], B2[q]);
        const v2f hB = fma2(A2[q], vB[q], B2[q]);
        accA = fma2(hA, vA[q], accA);
        accB = fma2(hB, vB[q], accB);
      }
      const float eA = exp2f(accA.x + accA.y + G);
      const float eB = exp2f(accB.x + accB.y + G);
      // interleaved softmax-sum chains (independent -> co-scheduled)
      float ua = eA, ub = eB;
      ua = dpp_add<0xB1>(ua);   ub = dpp_add<0xB1>(ub);
      ua = dpp_add<0x4E>(ua);   ub = dpp_add<0x4E>(ub);
      ua = dpp_add<0x141>(ua);  ub = dpp_add<0x141>(ub);
      ua = dpp_add<0x140>(ua);  ub = dpp_add<0x140>(ub);
      ua += __shfl_xor(ua, 16); ub += __shfl_xor(ub, 16);
      const float rrA = eA * rcpf(ua + 1e-37f) * sA[kA];   // r * a/(a+eps)
      const float rrB = eB * rcpf(ub + 1e-37f) * sA[kB];
      t0 += rrA + rrB;
      const v2f rA2 = bc2(rrA), rB2 = bc2(rrB);
#pragma unroll
      for (int q = 0; q < 8; ++q) {
        const v2f tA = rA2 * vA[q];
        const v2f tB = rB2 * vB[q];
        t1[q] += tA;
        t2[q] = fma2(tA, vA[q], t2[q]);
        t1[q] += tB;
        t2[q] = fma2(tB, vB[q], t2[q]);
      }
    }
    stats();
  }

  // ---- epilogue ----
  out[(size_t)n*544 + tid] = sMu[(tid>>4)*17 + (tid&15)];
  if (tid < CC) out[(size_t)n*544 + 512 + tid] = sAo[tid];
}

extern "C" void kernel_launch(void* const* d_in, const int* in_sizes, int n_in,
                              void* d_out, int out_size, void* d_ws, size_t ws_size,
                              hipStream_t stream) {
  (void)in_sizes; (void)n_in; (void)d_ws; (void)ws_size; (void)out_size;
  const float* x  = (const float*)d_in[0];
  const float* w  = (const float*)d_in[1];
  const float* ba = (const float*)d_in[2];
  const float* bu = (const float*)d_in[3];
  float* out = (float*)d_out;
  convcaps_em_kernel<<<dim3(392), dim3(NTH), 0, stream>>>(x, w, ba, bu, out);
}

// Round 20
// 122.353 us; speedup vs baseline: 1.1829x; 1.1829x over previous
//
#include <hip/hip_runtime.h>
#include <math.h>

// ConvCaps EM routing, fp32 I/O. n=392 positions, one 512-thread block each.
// FINAL (R20 = R15, measured session-best 75.9us; baseline R2 was 183us).
// Structure: single fused kernel, 3 v=P@W sweeps (one per EM iteration),
// packed fp32 (v_pk_fma), W software-pipeline from L2, DPP butterflies,
// shifted exp2 softmax with loop-invariant A/B/G quadratic form.
// Dead ends (measured): LDS register-prefetch (R12, +17%); 2 positions/block
// (R7, +40%); k-interleave (R16/R19 — compiler pins ~84 VGPR and serializes;
// __launch_bounds__ min-waves only CAPS the budget (R3/R8: spills), never
// raises it). Remaining gap is structural: chain-bound sweeps + 392-on-256
// block-atomic dispatch imbalance.

#define NTH 512
#define KK 288
#define KT 18         // 288 / 16 k-groups
#define CC 32
#define PS 16
#define EPSF 1e-8f
#define LAMF 1e-3f
#define HL2PI 0.91893853320467274178f   // 0.5*ln(2*pi)
#define LOG2E 1.4426950408889634f

typedef float v2f __attribute__((ext_vector_type(2)));

__device__ __forceinline__ float4 ld4(const float* p){ return *(const float4*)p; }
__device__ __forceinline__ float rcpf(float x){ return __builtin_amdgcn_rcpf(x); }
__device__ __forceinline__ v2f bc2(float s){ return (v2f){s, s}; }
__device__ __forceinline__ v2f fma2(v2f a, v2f b, v2f c){ return __builtin_elementwise_fma(a, b, c); }

// DPP cross-lane reduce steps (VALU pipe ~2-4cyc vs ds_swizzle ~30cyc).
template<int CTRL>
__device__ __forceinline__ float dpp_add(float x){
  const int p = __builtin_amdgcn_update_dpp(0, __builtin_bit_cast(int, x),
                                            CTRL, 0xF, 0xF, true);
  return x + __builtin_bit_cast(float, p);
}
template<int CTRL>
__device__ __forceinline__ float dpp_max(float x){
  const int p = __builtin_amdgcn_update_dpp(0, __builtin_bit_cast(int, x),
                                            CTRL, 0xF, 0xF, true);
  return fmaxf(x, __builtin_bit_cast(float, p));
}
__device__ __forceinline__ float sum32(float s){
  s = dpp_add<0xB1>(s); s = dpp_add<0x4E>(s);
  s = dpp_add<0x141>(s); s = dpp_add<0x140>(s);
  s += __shfl_xor(s, 16);
  return s;
}

extern "C" __global__ void __launch_bounds__(NTH)
convcaps_em_kernel(const float* __restrict__ x, const float* __restrict__ wgt,
                   const float* __restrict__ beta_a, const float* __restrict__ beta_u,
                   float* __restrict__ out)
{
  __shared__ float sP[KK*PS];        // poses, xor-swizzled groups (18432 B)
  __shared__ float sA[KK];           // f = a/(a+eps) (1152 B)
  __shared__ float sPart[8*CC*33];   // wave partials t0|t1[16]|t2[16] (33792 B)
  __shared__ float sMu[CC*17];       // (2176 B)
  __shared__ float sNI2[CC*17];      // -0.5/sigma^2 (2176 B)
  __shared__ float sLs[CC], sLnA[CC], sAo[CC];   // 384 B
  // total ~58.1 KB -> 2 blocks/CU

  const int tid = threadIdx.x;
  const int n   = blockIdx.x;
  const int b   = n / 49;
  const int r49 = n - b*49;
  const int ohi = r49 / 7;
  const int owi = r49 - ohi*7;

  const float* xw = x + ((size_t)b*16 + (size_t)(ohi*2))*16*544 + (size_t)(owi*2)*544;

  const int c  = tid & 31;    // sweep layout: c in-wave (softmax over c)
  const int ks = tid >> 5;    // k-group 0..15
  const int w  = tid >> 6;    // wave 0..7
  const int cc = tid >> 4;    // stats layout: one thread per (cc, pp)
  const int pp = tid & 15;

  // ---- stage poses (xor-swizzled groups) ----
  for (int idx = tid; idx < KK*PS/4; idx += NTH) {   // 1152 float4s
    const int sp  = idx >> 7;
    const int ch4 = idx & 127;
    const int kh = sp/3, kw = sp - kh*3;
    const float4 v = ld4(&xw[kh*(16*544) + kw*544 + ch4*4]);
    const int k = sp*32 + (ch4 >> 2);
    const int g = ch4 & 3;
    *(float4*)&sP[(k<<4) + ((g ^ ((k>>1)&3))<<2)] = v;
  }
  // ---- stage activations ----
  if (tid < KK/4) {
    const int sp  = tid >> 3;
    const int bc4 = tid & 7;
    const int kh = sp/3, kw = sp - kh*3;
    const float4 v = ld4(&xw[kh*(16*544) + kw*544 + 512 + bc4*4]);
    *(float4*)&sA[sp*32 + bc4*4] = v;
  }
  __syncthreads();
  if (tid < KK) { const float a = sA[tid]; sA[tid] = a * rcpf(a + EPSF); }
  __syncthreads();

  float t0;
  v2f t1[8], t2[8];    // packed moment accumulators

  // ---- stats phase (R6-proven layout; unpack pairs at store) ----
  auto stats = [&](){
    t0 += __shfl_xor(t0, 32);
#pragma unroll
    for (int q = 0; q < 8; ++q) {
      t1[q].x += __shfl_xor(t1[q].x, 32);
      t1[q].y += __shfl_xor(t1[q].y, 32);
      t2[q].x += __shfl_xor(t2[q].x, 32);
      t2[q].y += __shfl_xor(t2[q].y, 32);
    }
    if ((tid & 32) == 0) {
      float* pr = &sPart[(w*CC + c)*33];
      pr[0] = t0;
#pragma unroll
      for (int q = 0; q < 8; ++q) {
        pr[1 + 2*q]     = t1[q].x;  pr[1 + 2*q + 1]  = t1[q].y;
        pr[17 + 2*q]    = t2[q].x;  pr[17 + 2*q + 1] = t2[q].y;
      }
    }
    __syncthreads();
    {
      float T0 = 0.f, T1 = 0.f, T2 = 0.f;
#pragma unroll
      for (int j = 0; j < 8; ++j) {
        const float* pr = &sPart[(j*CC + cc)*33];
        T0 += pr[0]; T1 += pr[1+pp]; T2 += pr[17+pp];
      }
      const float z   = rcpf(T0 + EPSF);
      const float mu  = T1 * z;
      const float s0  = T0 * z;
      const float var = fmaxf(T2*z - mu*mu*(2.f - s0), 0.f) + EPSF;
      sMu[cc*17 + pp]  = mu;
      sNI2[cc*17 + pp] = -0.5f * rcpf(var);
      float lsum = 0.5f * __logf(var);
      lsum = dpp_add<0xB1>(lsum); lsum = dpp_add<0x4E>(lsum);
      lsum = dpp_add<0x141>(lsum); lsum = dpp_add<0x140>(lsum);
      if (pp == 0) {
        const float cost = (16.f*beta_u[cc] + lsum) * T0;   // r_sum = T0
        const float ao = rcpf(1.f + __expf(-(LAMF*(beta_a[cc] - cost))));
        sAo[cc] = ao; sLnA[cc] = __logf(ao); sLs[cc] = lsum;
      }
    }
    __syncthreads();
  };

  const float4* wg4 = (const float4*)wgt;

  // ---- sweep 0 (it=0): r uniform -> rr = f/32, W software-pipelined ----
  t0 = 0.f;
#pragma unroll
  for (int q = 0; q < 8; ++q) { t1[q] = bc2(0.f); t2[q] = bc2(0.f); }
  float4 cw0, cw1, cw2, cw3;
  {
    const size_t base = ((size_t)(ks*32 + c))*4;   // kt=0 -> k=ks
    cw0 = wg4[base]; cw1 = wg4[base+1]; cw2 = wg4[base+2]; cw3 = wg4[base+3];
  }
  for (int kt = 0; kt < KT; ++kt) {
    const int k = kt*16 + ks;
    const int kn = ((kt+1 < KT) ? kt+1 : kt)*16 + ks;
    float4 nw0, nw1, nw2, nw3;
    {
      const size_t base = ((size_t)(kn*32 + c))*4;
      nw0 = wg4[base]; nw1 = wg4[base+1]; nw2 = wg4[base+2]; nw3 = wg4[base+3];
    }
    const v2f w0lo = {cw0.x,cw0.y}, w0hi = {cw0.z,cw0.w};
    const v2f w1lo = {cw1.x,cw1.y}, w1hi = {cw1.z,cw1.w};
    const v2f w2lo = {cw2.x,cw2.y}, w2hi = {cw2.z,cw2.w};
    const v2f w3lo = {cw3.x,cw3.y}, w3hi = {cw3.z,cw3.w};
    const int sw = (k>>1)&3;
    const float* pb = &sP[k<<4];
    const float4 Pi[4] = { ld4(pb + ((0^sw)<<2)), ld4(pb + ((1^sw)<<2)),
                           ld4(pb + ((2^sw)<<2)), ld4(pb + ((3^sw)<<2)) };
    const float rr = sA[k] * (1.0f/32.0f);
    t0 += rr;
    const v2f rr2 = bc2(rr);
#pragma unroll
    for (int i = 0; i < 4; ++i) {
      v2f lo = bc2(Pi[i].x) * w0lo;
      lo = fma2(bc2(Pi[i].y), w1lo, lo);
      lo = fma2(bc2(Pi[i].z), w2lo, lo);
      lo = fma2(bc2(Pi[i].w), w3lo, lo);
      v2f hi = bc2(Pi[i].x) * w0hi;
      hi = fma2(bc2(Pi[i].y), w1hi, hi);
      hi = fma2(bc2(Pi[i].z), w2hi, hi);
      hi = fma2(bc2(Pi[i].w), w3hi, hi);
      const v2f mlo = rr2 * lo, mhi = rr2 * hi;
      t1[i*2]   += mlo;  t2[i*2]   = fma2(mlo, lo, t2[i*2]);
      t1[i*2+1] += mhi;  t2[i*2+1] = fma2(mhi, hi, t2[i*2+1]);
    }
    cw0 = nw0; cw1 = nw1; cw2 = nw2; cw3 = nw3;
  }
  stats();

  // ---- sweeps 1,2: exponent = Sum (A*v+B)*v + G; shifted exp2 softmax ----
  for (int it = 1; it < 3; ++it) {
    // loop-invariant per (sweep, c): A = log2e*ni2, B = -2*log2e*ni2*mu,
    // G = log2e*(Sum ni2*mu^2 + lcv - M)
    v2f A2[8], B2[8];
    float gsum = 0.f;
#pragma unroll
    for (int q = 0; q < 8; ++q) {
      const v2f m2 = (v2f){ sMu[c*17 + 2*q],  sMu[c*17 + 2*q + 1] };
      const v2f n2 = (v2f){ sNI2[c*17 + 2*q], sNI2[c*17 + 2*q + 1] };
      const v2f nm = n2 * m2;
      A2[q] = bc2(LOG2E) * n2;
      B2[q] = bc2(-2.f*LOG2E) * nm;
      const v2f g2 = nm * m2;
      gsum += g2.x + g2.y;
    }
    float lcv = sLnA[c] - sLs[c] - 16.f*HL2PI;
    float M = lcv;
    M = dpp_max<0xB1>(M);  M = dpp_max<0x4E>(M);
    M = dpp_max<0x141>(M); M = dpp_max<0x140>(M);
    M = fmaxf(M, __shfl_xor(M, 16));
    const float G = LOG2E*(gsum + lcv - M);
    t0 = 0.f;
#pragma unroll
    for (int q = 0; q < 8; ++q) { t1[q] = bc2(0.f); t2[q] = bc2(0.f); }
    {
      const size_t base = ((size_t)(ks*32 + c))*4;
      cw0 = wg4[base]; cw1 = wg4[base+1]; cw2 = wg4[base+2]; cw3 = wg4[base+3];
    }
    for (int kt = 0; kt < KT; ++kt) {
      const int k = kt*16 + ks;
      const int kn = ((kt+1 < KT) ? kt+1 : kt)*16 + ks;
      float4 nw0, nw1, nw2, nw3;
      {
        const size_t base = ((size_t)(kn*32 + c))*4;
        nw0 = wg4[base]; nw1 = wg4[base+1]; nw2 = wg4[base+2]; nw3 = wg4[base+3];
      }
      const v2f w0lo = {cw0.x,cw0.y}, w0hi = {cw0.z,cw0.w};
      const v2f w1lo = {cw1.x,cw1.y}, w1hi = {cw1.z,cw1.w};
      const v2f w2lo = {cw2.x,cw2.y}, w2hi = {cw2.z,cw2.w};
      const v2f w3lo = {cw3.x,cw3.y}, w3hi = {cw3.z,cw3.w};
      const int sw = (k>>1)&3;
      const float* pb = &sP[k<<4];
      const float4 Pi[4] = { ld4(pb + ((0^sw)<<2)), ld4(pb + ((1^sw)<<2)),
                             ld4(pb + ((2^sw)<<2)), ld4(pb + ((3^sw)<<2)) };
      v2f v[8];
#pragma unroll
      for (int i = 0; i < 4; ++i) {
        v2f lo = bc2(Pi[i].x) * w0lo;
        lo = fma2(bc2(Pi[i].y), w1lo, lo);
        lo = fma2(bc2(Pi[i].z), w2lo, lo);
        lo = fma2(bc2(Pi[i].w), w3lo, lo);
        v2f hi = bc2(Pi[i].x) * w0hi;
        hi = fma2(bc2(Pi[i].y), w1hi, hi);
        hi = fma2(bc2(Pi[i].z), w2hi, hi);
        hi = fma2(bc2(Pi[i].w), w3hi, hi);
        v[i*2] = lo; v[i*2+1] = hi;
      }
      v2f acc2 = bc2(0.f);
#pragma unroll
      for (int q = 0; q < 8; ++q) {
        const v2f h = fma2(A2[q], v[q], B2[q]);
        acc2 = fma2(h, v[q], acc2);
      }
      const float ex = acc2.x + acc2.y + G;      // log2-domain exponent <= ~0
      const float e = exp2f(ex);
      const float s = sum32(e);
      const float rr = e * rcpf(s + 1e-37f) * sA[k];   // r * a/(a+eps)
      t0 += rr;
      const v2f rr2 = bc2(rr);
#pragma unroll
      for (int q = 0; q < 8; ++q) {
        const v2f tmp = rr2 * v[q];
        t1[q] += tmp;
        t2[q] = fma2(tmp, v[q], t2[q]);
      }
      cw0 = nw0; cw1 = nw1; cw2 = nw2; cw3 = nw3;
    }
    stats();
  }

  // ---- epilogue ----
  out[(size_t)n*544 + tid] = sMu[(tid>>4)*17 + (tid&15)];
  if (tid < CC) out[(size_t)n*544 + 512 + tid] = sAo[tid];
}

extern "C" void kernel_launch(void* const* d_in, const int* in_sizes, int n_in,
                              void* d_out, int out_size, void* d_ws, size_t ws_size,
                              hipStream_t stream) {
  (void)in_sizes; (void)n_in; (void)d_ws; (void)ws_size; (void)out_size;
  const float* x  = (const float*)d_in[0];
  const float* w  = (const float*)d_in[1];
  const float* ba = (const float*)d_in[2];
  const float* bu = (const float*)d_in[3];
  float* out = (float*)d_out;
  convcaps_em_kernel<<<dim3(392), dim3(NTH), 0, stream>>>(x, w, ba, bu, out);
}